// Round 9
// baseline (38.613 us; speedup 1.0000x reference)
//
#include <hip/hip_runtime.h>

// LRP m-rule backward through AdaptiveAvgPool2d (56x56 -> 7x7, window 8x8, k=64).
//
// theta = 180deg => COS_T = -1.0 exactly, SIN_T ~ 1.2e-16. The chain collapses:
//   out_i = x_i * r / (Sx + 32*eps),  Sx = window sum (fp64: denominator can
// nearly cancel, min |denom| ~8e-7 over 401K windows). Divide in fp32.
//
// Round-9: round-5 structure (verified 38.4us, ideal traffic FETCH~58MB /
// WRITE~102MB), with the lane mapping swapped to w-minor/t-major:
//   w = lane&7 (window), t = lane>>3 (row).
// Adjacent lanes now cover adjacent windows -> each VMEM instruction's 16B
// pieces sit at 32B stride (2 lanes per 64B line) instead of 224B stride
// (1 lane per line): 2x fewer L1->L2 transactions per instruction. Little's-law
// analysis of rounds 5/7 shows concurrency is 3x what 6.3TB/s needs, so the
// 4.2TB/s plateau is a per-transaction throughput limit, not latency.
// Team reduce masks become xor 8,16,32 - same tree shape over t, so the fp64
// sum is bitwise identical to round 5 (absmax must stay exactly 768).
//
// Banned by measurement: NT stores (round 4: 2x write amplification),
// asm-hidden in-flight loads (round 8: stale register reads, no scoreboard).
//
// Grid: 50176 wave-groups = 7168 waves x 7 iters exact; 1792 blocks x 4 waves
// = 7 blocks/CU exact -> single resident pass, zero CU imbalance.

typedef float f32x4 __attribute__((ext_vector_type(4)));

static constexpr int HW     = 56 * 56;          // 3136
static constexpr int NWIN   = 8192 * 49;        // 401408 windows
static constexpr int NGRP   = NWIN / 8;         // 50176 wave-iterations
static constexpr int BLOCKS = 1792;             // 7 blocks/CU exact
static constexpr int WAVES  = BLOCKS * 4;       // 7168
static constexpr int NITER  = NGRP / WAVES;     // 7 (exact)

__global__ __launch_bounds__(256) void lrp_pool_kernel(
    const float* __restrict__ x,
    const float* __restrict__ r,
    float* __restrict__ out)
{
    const int tid  = threadIdx.x;
    const int lane = tid & 63;
    const int w    = lane & 7;    // window within the wave's group of 8
    const int t    = lane >> 3;   // team lane = window row

    const int g0 = blockIdx.x * 4 + (tid >> 6);

    #pragma unroll
    for (int it = 0; it < NITER; ++it) {
        const int g   = g0 + it * WAVES;
        const int wid = g * 8 + w;
        const int bc  = wid / 49;              // magic-mul div
        const int rem = wid - bc * 49;
        const int ohi = rem / 7;
        const int owi = rem - ohi * 7;

        const int base = bc * HW + (ohi * 8 + t) * 56 + owi * 8;
        const float* p = x + base;

        // one full window row: 2 contiguous 16B loads; adjacent lanes ->
        // adjacent windows -> 32B-stride pieces within each instruction
        const f32x4 a = *reinterpret_cast<const f32x4*>(p);
        const f32x4 b = *reinterpret_cast<const f32x4*>(p + 4);
        const float rv = r[wid];               // lanes t=0: coalesced; rest broadcast

        // fp64 per-lane row sum (tree), then 3-round butterfly across t
        // (masks 8,16,32: same tree shape over rows as round 5 -> identical sum)
        double s = (((double)a.x + (double)a.y) + ((double)a.z + (double)a.w))
                 + (((double)b.x + (double)b.y) + ((double)b.z + (double)b.w));
        s += __shfl_xor(s, 8,  64);
        s += __shfl_xor(s, 16, 64);
        s += __shfl_xor(s, 32, 64);

        const float coef = rv / (float)(s + 32.0 * 1e-5);

        *reinterpret_cast<f32x4*>(out + base)     = a * coef;
        *reinterpret_cast<f32x4*>(out + base + 4) = b * coef;
    }
}

extern "C" void kernel_launch(void* const* d_in, const int* in_sizes, int n_in,
                              void* d_out, int out_size, void* d_ws, size_t ws_size,
                              hipStream_t stream) {
    const float* x   = (const float*)d_in[0];
    const float* r   = (const float*)d_in[1];
    float*       out = (float*)d_out;
    lrp_pool_kernel<<<BLOCKS, 256, 0, stream>>>(x, r, out);
}